// Round 7
// baseline (161.795 us; speedup 1.0000x reference)
//
#include <hip/hip_runtime.h>

// Hierarchical sparse attention (binary tree), MI355X gfx950.
// B=4, S=4096, H=8, D=64, f32.
//
// v8: intra-wave tree reduction via __shfl_xor of 16-lane node fragments.
//  - Levels l1..l3 of every tree build are computed in registers with
//    xor16/xor32 group exchanges (no LDS, no barriers, all waves busy).
//  - chunk5: 1 barrier (was 5), LDS 17.9KB -> 2.2KB.
//  - attn32: l2/l3 computed by all groups in parallel (was: wave 0 serial,
//    14 LDS-round-trip combines between barriers); only l4 (2 combines)
//    remains between the two barriers.
//  - Note (R6): ~40-43us/iter of __amd_rocclr_fillBufferAligned (256MiB
//    workspace poison) is harness reset traffic inside the timed loop —
//    fixed floor, not addressable from kernel_launch.
// hi layout per bh (NHI=254 rows): [0,128)=l5, [128,192)=l6, [192,224)=l7,
// [224,240)=l8, [240,248)=l9, [248,252)=l10, [252,254)=l11.

#define S 4096
#define H 8
#define D 64
#define B 4
#define NBH 32
#define NHI 254
#define SCALE 0.125f
#define ROWF 68          // padded LDS row stride in floats

__device__ inline float red16(float x) {
    x += __shfl_xor(x, 1);
    x += __shfl_xor(x, 2);
    x += __shfl_xor(x, 4);
    x += __shfl_xor(x, 8);
    return x;
}

__device__ inline float dot4(const float4 a, const float4 b) {
    return a.x * b.x + a.y * b.y + a.z * b.z + a.w * b.w;
}

__device__ inline float4 shfl_xor4(const float4 x, int m) {
    float4 r;
    r.x = __shfl_xor(x.x, m);
    r.y = __shfl_xor(x.y, m);
    r.z = __shfl_xor(x.z, m);
    r.w = __shfl_xor(x.w, m);
    return r;
}

__device__ inline float4 sel4(bool c, const float4 a, const float4 b) {
    float4 r;
    r.x = c ? a.x : b.x;
    r.y = c ? a.y : b.y;
    r.z = c ? a.z : b.z;
    r.w = c ? a.w : b.w;
    return r;
}

// parent(k,v) from two children: softmax-weighted merge (16-lane reduce).
__device__ inline void combine(const float4 k0, const float4 k1,
                               const float4 v0, const float4 v1,
                               float4& kp, float4& vp) {
    kp.x = 0.5f * (k0.x + k1.x);
    kp.y = 0.5f * (k0.y + k1.y);
    kp.z = 0.5f * (k0.z + k1.z);
    kp.w = 0.5f * (k0.w + k1.w);
    float pss = red16(dot4(kp, kp)) * SCALE;
    float p0  = red16(dot4(kp, k0)) * SCALE;
    float p1  = red16(dot4(kp, k1)) * SCALE;
    float m  = fmaxf(pss, fmaxf(p0, p1));
    float es = __expf(pss - m), e0 = __expf(p0 - m), e1 = __expf(p1 - m);
    float inv = 1.0f / (es + e0 + e1 + 1e-9f);
    float h = 0.5f * es;
    vp.x = ((h + e0) * v0.x + (h + e1) * v1.x) * inv;
    vp.y = ((h + e0) * v0.y + (h + e1) * v1.y) * inv;
    vp.z = ((h + e0) * v0.z + (h + e1) * v1.z) * inv;
    vp.w = ((h + e0) * v0.w + (h + e1) * v1.w) * inv;
}

// K1: per (bh, pair of 32-leaf chunks): levels 1..5, write l5 roots.
// Group jg (0..7 per chunk) owns leaves 4jg..4jg+3; l1/l2 in regs,
// l3 via xor16, l4 via xor32, l5 via one 2-row LDS hop.
__global__ __launch_bounds__(256, 6) void chunk5(
    const float* __restrict__ k, const float* __restrict__ v,
    float* __restrict__ khi, float* __restrict__ vhi)
{
    __shared__ float l4k[4 * ROWF], l4v[4 * ROWF];   // 2 chunks x 2 l4 rows
    const int t = threadIdx.x;
    const int sub = t & 15;
    const int pg = t >> 4;
    const int blk = blockIdx.x;
    const int pair = blk & 63;
    const int bh = blk >> 6;
    const int b = bh >> 3, h = bh & 7;
    const int csel = pg >> 3;           // 0 or 1
    const int jg = pg & 7;
    const int c = pair * 2 + csel;      // 0..127

    const int s0 = c * 32 + 4 * jg;
    const size_t a0 = ((((size_t)b * S + s0) * H + h) * D) + sub * 4;
    float4 kA = *(const float4*)(k + a0);
    float4 kB = *(const float4*)(k + a0 + H * D);
    float4 kC = *(const float4*)(k + a0 + 2 * H * D);
    float4 kD = *(const float4*)(k + a0 + 3 * H * D);
    float4 vA = *(const float4*)(v + a0);
    float4 vB = *(const float4*)(v + a0 + H * D);
    float4 vC = *(const float4*)(v + a0 + 2 * H * D);
    float4 vD = *(const float4*)(v + a0 + 3 * H * D);

    float4 k1a, v1a, k1b, v1b, k2, v2;
    combine(kA, kB, vA, vB, k1a, v1a);         // l1 node 2jg
    combine(kC, kD, vC, vD, k1b, v1b);         // l1 node 2jg+1
    combine(k1a, k1b, v1a, v1b, k2, v2);       // l2 node jg

    // l3 node jg>>1 via xor16 (partner group jg^1, same wave)
    float4 p2k = shfl_xor4(k2, 16), p2v = shfl_xor4(v2, 16);
    float4 k3, v3;
    combine(sel4(jg & 1, p2k, k2), sel4(jg & 1, k2, p2k),
            sel4(jg & 1, p2v, v2), sel4(jg & 1, v2, p2v), k3, v3);

    // l4 node jg>>2 via xor32 (partner group jg^2, same wave)
    float4 p3k = shfl_xor4(k3, 32), p3v = shfl_xor4(v3, 32);
    float4 k4, v4;
    combine(sel4(jg & 2, p3k, k3), sel4(jg & 2, k3, p3k),
            sel4(jg & 2, p3v, v3), sel4(jg & 2, v3, p3v), k4, v4);

    if ((jg & 3) == 0) {                       // one writer per l4 node
        int row = csel * 2 + (jg >> 2);
        *(float4*)(l4k + row * ROWF + sub * 4) = k4;
        *(float4*)(l4v + row * ROWF + sub * 4) = v4;
    }
    __syncthreads();
    if (jg == 0) {                             // l5 root of this chunk
        int r0 = csel * 2, r1 = csel * 2 + 1;
        float4 ka4 = *(const float4*)(l4k + r0 * ROWF + sub * 4);
        float4 kb4 = *(const float4*)(l4k + r1 * ROWF + sub * 4);
        float4 va4 = *(const float4*)(l4v + r0 * ROWF + sub * 4);
        float4 vb4 = *(const float4*)(l4v + r1 * ROWF + sub * 4);
        float4 kp, vp;
        combine(ka4, kb4, va4, vb4, kp, vp);
        size_t g = ((size_t)bh * NHI + c) * 64 + sub * 4;
        *(float4*)(khi + g) = kp;
        *(float4*)(vhi + g) = vp;
    }
}

// K2: 64 blocks. Block (bh, half) builds levels 6..11 for its disjoint
// 64-root half-subtree.
__global__ __launch_bounds__(256) void build_hi_half(
    float* __restrict__ khi, float* __restrict__ vhi)
{
    __shared__ float lk[64 * ROWF], lv[64 * ROWF];
    const int t = threadIdx.x;
    const int sub = t & 15;
    const int pg = t >> 4;
    const int bh = blockIdx.x >> 1;
    const int half = blockIdx.x & 1;
    size_t base = (size_t)bh * NHI * 64;
    const int rootO = half * 64;

    for (int i = t; i < 1024; i += 256) {
        int row = i >> 4, s16 = i & 15;
        *(float4*)(lk + row * ROWF + s16 * 4) =
            *(const float4*)(khi + base + (size_t)(rootO + row) * 64 + s16 * 4);
        *(float4*)(lv + row * ROWF + s16 * 4) =
            *(const float4*)(vhi + base + (size_t)(rootO + row) * 64 + s16 * 4);
    }
    __syncthreads();

#pragma unroll
    for (int tt = 1; tt <= 6; ++tt) {
        int nodes = 64 >> tt;                 // 32,16,8,4,2,1 (per half)
        int off = 256 - (256 >> tt);          // 128,192,224,240,248,252
        for (int j = pg; j < nodes; j += 16) {
            int r0 = (2 * j) << (tt - 1);
            int r1 = (2 * j + 1) << (tt - 1);
            float4 k0 = *(const float4*)(lk + r0 * ROWF + sub * 4);
            float4 k1 = *(const float4*)(lk + r1 * ROWF + sub * 4);
            float4 v0 = *(const float4*)(lv + r0 * ROWF + sub * 4);
            float4 v1 = *(const float4*)(lv + r1 * ROWF + sub * 4);
            float4 kp, vp;
            combine(k0, k1, v0, v1, kp, vp);
            *(float4*)(lk + (j << tt) * ROWF + sub * 4) = kp;
            *(float4*)(lv + (j << tt) * ROWF + sub * 4) = vp;
            size_t g = base + (size_t)(off + half * nodes + j) * 64 + sub * 4;
            *(float4*)(khi + g) = kp;
            *(float4*)(vhi + g) = vp;
        }
        __syncthreads();
    }
}

// K3: attention. Block = (bh, 32-query chunk). Group pg -> queries 2pg,2pg+1.
__global__ __launch_bounds__(256, 7) void attn32(
    const float* __restrict__ q, const float* __restrict__ k,
    const float* __restrict__ v,
    const float* __restrict__ khi, const float* __restrict__ vhi,
    float* __restrict__ out)
{
    __shared__ float tk[30 * ROWF], tv[30 * ROWF];   // l1:0-15 l2:16-23 l3:24-27 l4:28-29
    __shared__ float pk[7 * ROWF], pv[7 * ROWF];     // path l5..11
    const int t = threadIdx.x;
    const int sub = t & 15;
    const int pg = t >> 4;
    const int blk = blockIdx.x;
    const int c32 = blk & 127;
    const int bh = blk >> 7;
    const int b = bh >> 3, h = bh & 7;

    // stage path nodes (block-uniform): groups 0..6 -> pk, 8..14 -> pv
    {
        int pl = (pg < 7) ? pg : pg - 8;
        if (pl >= 0 && pl < 7 && pg != 7 && pg != 15) {
            if ((c32 >> pl) & 1) {
                int off = 256 - (256 >> pl);     // 0,128,192,224,240,248,252
                int node = off + ((c32 >> pl) ^ 1);
                size_t a = ((size_t)bh * NHI + node) * 64 + sub * 4;
                if (pg < 7) *(float4*)(pk + pl * ROWF + sub * 4) = *(const float4*)(khi + a);
                else        *(float4*)(pv + pl * ROWF + sub * 4) = *(const float4*)(vhi + a);
            }
        }
    }

    // leaves + queries for this group's two queries (all global loads upfront)
    const int s0 = c32 * 32 + 2 * pg;
    const size_t a0 = ((((size_t)b * S + s0) * H + h) * D) + sub * 4;
    const float4 k0 = *(const float4*)(k + a0);
    const float4 k1 = *(const float4*)(k + a0 + H * D);
    const float4 v0 = *(const float4*)(v + a0);
    const float4 v1 = *(const float4*)(v + a0 + H * D);
    const float4 q0 = *(const float4*)(q + a0);
    const float4 q1 = *(const float4*)(q + a0 + H * D);

    // l1 node pg (regs) -> LDS
    float4 t1k, t1v;
    combine(k0, k1, v0, v1, t1k, t1v);
    *(float4*)(tk + pg * ROWF + sub * 4) = t1k;
    *(float4*)(tv + pg * ROWF + sub * 4) = t1v;

    // l2 node pg>>1 via xor16
    float4 p2k = shfl_xor4(t1k, 16), p2v = shfl_xor4(t1v, 16);
    float4 t2k, t2v;
    combine(sel4(pg & 1, p2k, t1k), sel4(pg & 1, t1k, p2k),
            sel4(pg & 1, p2v, t1v), sel4(pg & 1, t1v, p2v), t2k, t2v);
    if ((pg & 1) == 0) {
        *(float4*)(tk + (16 + (pg >> 1)) * ROWF + sub * 4) = t2k;
        *(float4*)(tv + (16 + (pg >> 1)) * ROWF + sub * 4) = t2v;
    }

    // l3 node pg>>2 via xor32
    float4 p3k = shfl_xor4(t2k, 32), p3v = shfl_xor4(t2v, 32);
    float4 t3k, t3v;
    combine(sel4(pg & 2, p3k, t2k), sel4(pg & 2, t2k, p3k),
            sel4(pg & 2, p3v, t2v), sel4(pg & 2, t2v, p3v), t3k, t3v);
    if ((pg & 3) == 0) {
        *(float4*)(tk + (24 + (pg >> 2)) * ROWF + sub * 4) = t3k;
        *(float4*)(tv + (24 + (pg >> 2)) * ROWF + sub * 4) = t3v;
    }
    __syncthreads();

    // l4: 2 combines from LDS l3 rows (cross-wave)
    if (pg < 2) {
        float4 ka = *(const float4*)(tk + (24 + 2 * pg) * ROWF + sub * 4);
        float4 kb = *(const float4*)(tk + (24 + 2 * pg + 1) * ROWF + sub * 4);
        float4 va = *(const float4*)(tv + (24 + 2 * pg) * ROWF + sub * 4);
        float4 vb = *(const float4*)(tv + (24 + 2 * pg + 1) * ROWF + sub * 4);
        float4 kp, vp;
        combine(ka, kb, va, vb, kp, vp);
        *(float4*)(tk + (28 + pg) * ROWF + sub * 4) = kp;
        *(float4*)(tv + (28 + pg) * ROWF + sub * 4) = vp;
    }
    __syncthreads();

    // scoring: r=0 -> even query 2pg (self=leaf0); r=1 -> odd 2pg+1
#pragma unroll
    for (int r = 0; r < 2; ++r) {
        const int s = s0 + r;
        const float4 q4 = r ? q1 : q0;
        const float4 k4 = r ? k1 : k0;
        const float4 v4 = r ? v1 : v0;

        float ss = red16(dot4(q4, k4)) * SCALE;

        float sc[12];
        if (r) sc[0] = red16(dot4(q4, k0)) * SCALE;
        else   sc[0] = -1e38f;
#pragma unroll
        for (int l = 1; l <= 4; ++l) {
            if ((s >> l) & 1) {
                int base = 32 - (32 >> (l - 1));          // 0,16,24,28
                int loc = base + (((s >> l) ^ 1) - (c32 << (5 - l)));
                float4 kc = *(const float4*)(tk + loc * ROWF + sub * 4);
                sc[l] = red16(dot4(q4, kc)) * SCALE;
            } else sc[l] = -1e38f;
        }
#pragma unroll
        for (int l = 5; l <= 11; ++l) {
            if ((c32 >> (l - 5)) & 1) {                   // == bit l of s
                float4 kc = *(const float4*)(pk + (l - 5) * ROWF + sub * 4);
                sc[l] = red16(dot4(q4, kc)) * SCALE;
            } else sc[l] = -1e38f;
        }

        float m = ss;
#pragma unroll
        for (int l = 0; l < 12; ++l) m = fmaxf(m, sc[l]);

        float es = __expf(ss - m);
        float denom = es;
        float4 acc;
        acc.x = es * v4.x; acc.y = es * v4.y;
        acc.z = es * v4.z; acc.w = es * v4.w;

        if (r) {
            float e = __expf(sc[0] - m);
            denom += e;
            acc.x += e * v0.x; acc.y += e * v0.y;
            acc.z += e * v0.z; acc.w += e * v0.w;
        }
#pragma unroll
        for (int l = 1; l <= 4; ++l) {
            if ((s >> l) & 1) {
                int base = 32 - (32 >> (l - 1));
                int loc = base + (((s >> l) ^ 1) - (c32 << (5 - l)));
                float4 vc = *(const float4*)(tv + loc * ROWF + sub * 4);
                float e = __expf(sc[l] - m);
                denom += e;
                acc.x += e * vc.x; acc.y += e * vc.y;
                acc.z += e * vc.z; acc.w += e * vc.w;
            }
        }
#pragma unroll
        for (int l = 5; l <= 11; ++l) {
            if ((c32 >> (l - 5)) & 1) {
                float4 vc = *(const float4*)(pv + (l - 5) * ROWF + sub * 4);
                float e = __expf(sc[l] - m);
                denom += e;
                acc.x += e * vc.x; acc.y += e * vc.y;
                acc.z += e * vc.z; acc.w += e * vc.w;
            }
        }
        float inv = 1.0f / denom;
        float4 o;
        o.x = acc.x * inv; o.y = acc.y * inv;
        o.z = acc.z * inv; o.w = acc.w * inv;
        *(float4*)(out + a0 + r * H * D) = o;
    }
}

extern "C" void kernel_launch(void* const* d_in, const int* in_sizes, int n_in,
                              void* d_out, int out_size, void* d_ws, size_t ws_size,
                              hipStream_t stream) {
    const float* q = (const float*)d_in[0];
    const float* k = (const float*)d_in[1];
    const float* v = (const float*)d_in[2];
    float* outp = (float*)d_out;
    float* khi = (float*)d_ws;                      // 32*254*64 f32 ~= 2.1 MB
    float* vhi = khi + (size_t)NBH * NHI * D;

    hipLaunchKernelGGL(chunk5, dim3(NBH * 64), dim3(256), 0, stream,
                       k, v, khi, vhi);
    hipLaunchKernelGGL(build_hi_half, dim3(NBH * 2), dim3(256), 0, stream,
                       khi, vhi);
    hipLaunchKernelGGL(attn32, dim3(NBH * 128), dim3(256), 0, stream,
                       q, k, v, khi, vhi, outp);
}

// Round 8
// 157.405 us; speedup vs baseline: 1.0279x; 1.0279x over previous
//
#include <hip/hip_runtime.h>

// Hierarchical sparse attention (binary tree), MI355X gfx950.
// B=4, S=4096, H=8, D=64, f32.
//
// v9: v8 minus the measured VALU regression.
//  - attn32 keeps v8's register reuse (query pair 2pg/2pg+1: self k/v,
//    l0 sibling, and l1 operands come from the leaf registers; all global
//    loads issued before the first barrier; FETCH 85->52 MB) but reverts
//    the tree build to the minimal-work LDS ladder (l1:16, l2:8, l3:4,
//    l4:2 group-combines, 4 barriers). v8's xor16/xor32 build duplicated
//    l2/l3 combines 2-4x (50 vs 30 group-combines) and cost +7.4us at
//    ~19 waves/CU where VALU throughput, not latency, is the margin.
//  - chunk5 stays v8 (1 barrier, 2.2KB LDS): its redundancy sits under a
//    ~10.6us HBM floor for the 67MB leaf read.
//  - R6 note: ~40-43us/iter __amd_rocclr_fillBufferAligned (256MiB ws
//    poison) is harness reset inside the timed loop — fixed floor.
// hi layout per bh (NHI=254 rows): [0,128)=l5, [128,192)=l6, [192,224)=l7,
// [224,240)=l8, [240,248)=l9, [248,252)=l10, [252,254)=l11.

#define S 4096
#define H 8
#define D 64
#define B 4
#define NBH 32
#define NHI 254
#define SCALE 0.125f
#define ROWF 68          // padded LDS row stride in floats

__device__ inline float red16(float x) {
    x += __shfl_xor(x, 1);
    x += __shfl_xor(x, 2);
    x += __shfl_xor(x, 4);
    x += __shfl_xor(x, 8);
    return x;
}

__device__ inline float dot4(const float4 a, const float4 b) {
    return a.x * b.x + a.y * b.y + a.z * b.z + a.w * b.w;
}

__device__ inline float4 shfl_xor4(const float4 x, int m) {
    float4 r;
    r.x = __shfl_xor(x.x, m);
    r.y = __shfl_xor(x.y, m);
    r.z = __shfl_xor(x.z, m);
    r.w = __shfl_xor(x.w, m);
    return r;
}

__device__ inline float4 sel4(bool c, const float4 a, const float4 b) {
    float4 r;
    r.x = c ? a.x : b.x;
    r.y = c ? a.y : b.y;
    r.z = c ? a.z : b.z;
    r.w = c ? a.w : b.w;
    return r;
}

// parent(k,v) from two children: softmax-weighted merge (16-lane reduce).
__device__ inline void combine(const float4 k0, const float4 k1,
                               const float4 v0, const float4 v1,
                               float4& kp, float4& vp) {
    kp.x = 0.5f * (k0.x + k1.x);
    kp.y = 0.5f * (k0.y + k1.y);
    kp.z = 0.5f * (k0.z + k1.z);
    kp.w = 0.5f * (k0.w + k1.w);
    float pss = red16(dot4(kp, kp)) * SCALE;
    float p0  = red16(dot4(kp, k0)) * SCALE;
    float p1  = red16(dot4(kp, k1)) * SCALE;
    float m  = fmaxf(pss, fmaxf(p0, p1));
    float es = __expf(pss - m), e0 = __expf(p0 - m), e1 = __expf(p1 - m);
    float inv = 1.0f / (es + e0 + e1 + 1e-9f);
    float h = 0.5f * es;
    vp.x = ((h + e0) * v0.x + (h + e1) * v1.x) * inv;
    vp.y = ((h + e0) * v0.y + (h + e1) * v1.y) * inv;
    vp.z = ((h + e0) * v0.z + (h + e1) * v1.z) * inv;
    vp.w = ((h + e0) * v0.w + (h + e1) * v1.w) * inv;
}

// K1: per (bh, pair of 32-leaf chunks): levels 1..5, write l5 roots.
// Group jg (0..7 per chunk) owns leaves 4jg..4jg+3; l1/l2 in regs,
// l3 via xor16, l4 via xor32, l5 via one 2-row LDS hop.
__global__ __launch_bounds__(256, 6) void chunk5(
    const float* __restrict__ k, const float* __restrict__ v,
    float* __restrict__ khi, float* __restrict__ vhi)
{
    __shared__ float l4k[4 * ROWF], l4v[4 * ROWF];   // 2 chunks x 2 l4 rows
    const int t = threadIdx.x;
    const int sub = t & 15;
    const int pg = t >> 4;
    const int blk = blockIdx.x;
    const int pair = blk & 63;
    const int bh = blk >> 6;
    const int b = bh >> 3, h = bh & 7;
    const int csel = pg >> 3;           // 0 or 1
    const int jg = pg & 7;
    const int c = pair * 2 + csel;      // 0..127

    const int s0 = c * 32 + 4 * jg;
    const size_t a0 = ((((size_t)b * S + s0) * H + h) * D) + sub * 4;
    float4 kA = *(const float4*)(k + a0);
    float4 kB = *(const float4*)(k + a0 + H * D);
    float4 kC = *(const float4*)(k + a0 + 2 * H * D);
    float4 kD = *(const float4*)(k + a0 + 3 * H * D);
    float4 vA = *(const float4*)(v + a0);
    float4 vB = *(const float4*)(v + a0 + H * D);
    float4 vC = *(const float4*)(v + a0 + 2 * H * D);
    float4 vD = *(const float4*)(v + a0 + 3 * H * D);

    float4 k1a, v1a, k1b, v1b, k2, v2;
    combine(kA, kB, vA, vB, k1a, v1a);         // l1 node 2jg
    combine(kC, kD, vC, vD, k1b, v1b);         // l1 node 2jg+1
    combine(k1a, k1b, v1a, v1b, k2, v2);       // l2 node jg

    // l3 node jg>>1 via xor16 (partner group jg^1, same wave)
    float4 p2k = shfl_xor4(k2, 16), p2v = shfl_xor4(v2, 16);
    float4 k3, v3;
    combine(sel4(jg & 1, p2k, k2), sel4(jg & 1, k2, p2k),
            sel4(jg & 1, p2v, v2), sel4(jg & 1, v2, p2v), k3, v3);

    // l4 node jg>>2 via xor32 (partner group jg^2, same wave)
    float4 p3k = shfl_xor4(k3, 32), p3v = shfl_xor4(v3, 32);
    float4 k4, v4;
    combine(sel4(jg & 2, p3k, k3), sel4(jg & 2, k3, p3k),
            sel4(jg & 2, p3v, v3), sel4(jg & 2, v3, p3v), k4, v4);

    if ((jg & 3) == 0) {                       // one writer per l4 node
        int row = csel * 2 + (jg >> 2);
        *(float4*)(l4k + row * ROWF + sub * 4) = k4;
        *(float4*)(l4v + row * ROWF + sub * 4) = v4;
    }
    __syncthreads();
    if (jg == 0) {                             // l5 root of this chunk
        int r0 = csel * 2, r1 = csel * 2 + 1;
        float4 ka4 = *(const float4*)(l4k + r0 * ROWF + sub * 4);
        float4 kb4 = *(const float4*)(l4k + r1 * ROWF + sub * 4);
        float4 va4 = *(const float4*)(l4v + r0 * ROWF + sub * 4);
        float4 vb4 = *(const float4*)(l4v + r1 * ROWF + sub * 4);
        float4 kp, vp;
        combine(ka4, kb4, va4, vb4, kp, vp);
        size_t g = ((size_t)bh * NHI + c) * 64 + sub * 4;
        *(float4*)(khi + g) = kp;
        *(float4*)(vhi + g) = vp;
    }
}

// K2: 64 blocks. Block (bh, half) builds levels 6..11 for its disjoint
// 64-root half-subtree.
__global__ __launch_bounds__(256) void build_hi_half(
    float* __restrict__ khi, float* __restrict__ vhi)
{
    __shared__ float lk[64 * ROWF], lv[64 * ROWF];
    const int t = threadIdx.x;
    const int sub = t & 15;
    const int pg = t >> 4;
    const int bh = blockIdx.x >> 1;
    const int half = blockIdx.x & 1;
    size_t base = (size_t)bh * NHI * 64;
    const int rootO = half * 64;

    for (int i = t; i < 1024; i += 256) {
        int row = i >> 4, s16 = i & 15;
        *(float4*)(lk + row * ROWF + s16 * 4) =
            *(const float4*)(khi + base + (size_t)(rootO + row) * 64 + s16 * 4);
        *(float4*)(lv + row * ROWF + s16 * 4) =
            *(const float4*)(vhi + base + (size_t)(rootO + row) * 64 + s16 * 4);
    }
    __syncthreads();

#pragma unroll
    for (int tt = 1; tt <= 6; ++tt) {
        int nodes = 64 >> tt;                 // 32,16,8,4,2,1 (per half)
        int off = 256 - (256 >> tt);          // 128,192,224,240,248,252
        for (int j = pg; j < nodes; j += 16) {
            int r0 = (2 * j) << (tt - 1);
            int r1 = (2 * j + 1) << (tt - 1);
            float4 k0 = *(const float4*)(lk + r0 * ROWF + sub * 4);
            float4 k1 = *(const float4*)(lk + r1 * ROWF + sub * 4);
            float4 v0 = *(const float4*)(lv + r0 * ROWF + sub * 4);
            float4 v1 = *(const float4*)(lv + r1 * ROWF + sub * 4);
            float4 kp, vp;
            combine(k0, k1, v0, v1, kp, vp);
            *(float4*)(lk + (j << tt) * ROWF + sub * 4) = kp;
            *(float4*)(lv + (j << tt) * ROWF + sub * 4) = vp;
            size_t g = base + (size_t)(off + half * nodes + j) * 64 + sub * 4;
            *(float4*)(khi + g) = kp;
            *(float4*)(vhi + g) = vp;
        }
        __syncthreads();
    }
}

// K3: attention. Block = (bh, 32-query chunk). Group pg -> queries 2pg,2pg+1.
// Tree build: minimal-work LDS ladder (l1:16, l2:8, l3:4, l4:2 combines).
__global__ __launch_bounds__(256, 8) void attn32(
    const float* __restrict__ q, const float* __restrict__ k,
    const float* __restrict__ v,
    const float* __restrict__ khi, const float* __restrict__ vhi,
    float* __restrict__ out)
{
    __shared__ float tk[30 * ROWF], tv[30 * ROWF];   // l1:0-15 l2:16-23 l3:24-27 l4:28-29
    __shared__ float pk[7 * ROWF], pv[7 * ROWF];     // path l5..11
    const int t = threadIdx.x;
    const int sub = t & 15;
    const int pg = t >> 4;
    const int blk = blockIdx.x;
    const int c32 = blk & 127;
    const int bh = blk >> 7;
    const int b = bh >> 3, h = bh & 7;

    // stage path nodes (block-uniform): groups 0..6 -> pk, 8..14 -> pv
    {
        int pl = (pg < 7) ? pg : pg - 8;
        if (pl >= 0 && pl < 7 && pg != 7 && pg != 15) {
            if ((c32 >> pl) & 1) {
                int off = 256 - (256 >> pl);     // 0,128,192,224,240,248,252
                int node = off + ((c32 >> pl) ^ 1);
                size_t a = ((size_t)bh * NHI + node) * 64 + sub * 4;
                if (pg < 7) *(float4*)(pk + pl * ROWF + sub * 4) = *(const float4*)(khi + a);
                else        *(float4*)(pv + pl * ROWF + sub * 4) = *(const float4*)(vhi + a);
            }
        }
    }

    // leaves + queries for this group's two queries (all global loads upfront)
    const int s0 = c32 * 32 + 2 * pg;
    const size_t a0 = ((((size_t)b * S + s0) * H + h) * D) + sub * 4;
    const float4 k0 = *(const float4*)(k + a0);
    const float4 k1 = *(const float4*)(k + a0 + H * D);
    const float4 v0 = *(const float4*)(v + a0);
    const float4 v1 = *(const float4*)(v + a0 + H * D);
    const float4 q0 = *(const float4*)(q + a0);
    const float4 q1 = *(const float4*)(q + a0 + H * D);

    // l1 node pg from held leaf registers
    {
        float4 kp, vp;
        combine(k0, k1, v0, v1, kp, vp);
        *(float4*)(tk + pg * ROWF + sub * 4) = kp;
        *(float4*)(tv + pg * ROWF + sub * 4) = vp;
    }
    __syncthreads();

    // l2: 8 combines -> rows 16..23
    if (pg < 8) {
        float4 ka = *(const float4*)(tk + (2 * pg) * ROWF + sub * 4);
        float4 kb = *(const float4*)(tk + (2 * pg + 1) * ROWF + sub * 4);
        float4 va = *(const float4*)(tv + (2 * pg) * ROWF + sub * 4);
        float4 vb = *(const float4*)(tv + (2 * pg + 1) * ROWF + sub * 4);
        float4 kp, vp;
        combine(ka, kb, va, vb, kp, vp);
        *(float4*)(tk + (16 + pg) * ROWF + sub * 4) = kp;
        *(float4*)(tv + (16 + pg) * ROWF + sub * 4) = vp;
    }
    __syncthreads();

    // l3: 4 combines -> rows 24..27
    if (pg < 4) {
        float4 ka = *(const float4*)(tk + (16 + 2 * pg) * ROWF + sub * 4);
        float4 kb = *(const float4*)(tk + (16 + 2 * pg + 1) * ROWF + sub * 4);
        float4 va = *(const float4*)(tv + (16 + 2 * pg) * ROWF + sub * 4);
        float4 vb = *(const float4*)(tv + (16 + 2 * pg + 1) * ROWF + sub * 4);
        float4 kp, vp;
        combine(ka, kb, va, vb, kp, vp);
        *(float4*)(tk + (24 + pg) * ROWF + sub * 4) = kp;
        *(float4*)(tv + (24 + pg) * ROWF + sub * 4) = vp;
    }
    __syncthreads();

    // l4: 2 combines -> rows 28..29
    if (pg < 2) {
        float4 ka = *(const float4*)(tk + (24 + 2 * pg) * ROWF + sub * 4);
        float4 kb = *(const float4*)(tk + (24 + 2 * pg + 1) * ROWF + sub * 4);
        float4 va = *(const float4*)(tv + (24 + 2 * pg) * ROWF + sub * 4);
        float4 vb = *(const float4*)(tv + (24 + 2 * pg + 1) * ROWF + sub * 4);
        float4 kp, vp;
        combine(ka, kb, va, vb, kp, vp);
        *(float4*)(tk + (28 + pg) * ROWF + sub * 4) = kp;
        *(float4*)(tv + (28 + pg) * ROWF + sub * 4) = vp;
    }
    __syncthreads();

    // scoring: r=0 -> even query 2pg (self=leaf0); r=1 -> odd 2pg+1
    // (self=leaf1, l0 sibling=leaf0) — all from registers.
#pragma unroll
    for (int r = 0; r < 2; ++r) {
        const int s = s0 + r;
        const float4 q4 = r ? q1 : q0;
        const float4 k4 = r ? k1 : k0;
        const float4 v4 = r ? v1 : v0;

        float ss = red16(dot4(q4, k4)) * SCALE;

        float sc[12];
        if (r) sc[0] = red16(dot4(q4, k0)) * SCALE;
        else   sc[0] = -1e38f;
#pragma unroll
        for (int l = 1; l <= 4; ++l) {
            if ((s >> l) & 1) {
                int base = 32 - (32 >> (l - 1));          // 0,16,24,28
                int loc = base + (((s >> l) ^ 1) - (c32 << (5 - l)));
                float4 kc = *(const float4*)(tk + loc * ROWF + sub * 4);
                sc[l] = red16(dot4(q4, kc)) * SCALE;
            } else sc[l] = -1e38f;
        }
#pragma unroll
        for (int l = 5; l <= 11; ++l) {
            if ((c32 >> (l - 5)) & 1) {                   // == bit l of s
                float4 kc = *(const float4*)(pk + (l - 5) * ROWF + sub * 4);
                sc[l] = red16(dot4(q4, kc)) * SCALE;
            } else sc[l] = -1e38f;
        }

        float m = ss;
#pragma unroll
        for (int l = 0; l < 12; ++l) m = fmaxf(m, sc[l]);

        float es = __expf(ss - m);
        float denom = es;
        float4 acc;
        acc.x = es * v4.x; acc.y = es * v4.y;
        acc.z = es * v4.z; acc.w = es * v4.w;

        if (r) {
            float e = __expf(sc[0] - m);
            denom += e;
            acc.x += e * v0.x; acc.y += e * v0.y;
            acc.z += e * v0.z; acc.w += e * v0.w;
        }
#pragma unroll
        for (int l = 1; l <= 4; ++l) {
            if ((s >> l) & 1) {
                int base = 32 - (32 >> (l - 1));
                int loc = base + (((s >> l) ^ 1) - (c32 << (5 - l)));
                float4 vc = *(const float4*)(tv + loc * ROWF + sub * 4);
                float e = __expf(sc[l] - m);
                denom += e;
                acc.x += e * vc.x; acc.y += e * vc.y;
                acc.z += e * vc.z; acc.w += e * vc.w;
            }
        }
#pragma unroll
        for (int l = 5; l <= 11; ++l) {
            if ((c32 >> (l - 5)) & 1) {
                float4 vc = *(const float4*)(pv + (l - 5) * ROWF + sub * 4);
                float e = __expf(sc[l] - m);
                denom += e;
                acc.x += e * vc.x; acc.y += e * vc.y;
                acc.z += e * vc.z; acc.w += e * vc.w;
            }
        }
        float inv = 1.0f / denom;
        float4 o;
        o.x = acc.x * inv; o.y = acc.y * inv;
        o.z = acc.z * inv; o.w = acc.w * inv;
        *(float4*)(out + a0 + r * H * D) = o;
    }
}

extern "C" void kernel_launch(void* const* d_in, const int* in_sizes, int n_in,
                              void* d_out, int out_size, void* d_ws, size_t ws_size,
                              hipStream_t stream) {
    const float* q = (const float*)d_in[0];
    const float* k = (const float*)d_in[1];
    const float* v = (const float*)d_in[2];
    float* outp = (float*)d_out;
    float* khi = (float*)d_ws;                      // 32*254*64 f32 ~= 2.1 MB
    float* vhi = khi + (size_t)NBH * NHI * D;

    hipLaunchKernelGGL(chunk5, dim3(NBH * 64), dim3(256), 0, stream,
                       k, v, khi, vhi);
    hipLaunchKernelGGL(build_hi_half, dim3(NBH * 2), dim3(256), 0, stream,
                       khi, vhi);
    hipLaunchKernelGGL(attn32, dim3(NBH * 128), dim3(256), 0, stream,
                       q, k, v, khi, vhi, outp);
}

// Round 9
// 149.683 us; speedup vs baseline: 1.0809x; 1.0516x over previous
//
#include <hip/hip_runtime.h>

// Hierarchical sparse attention (binary tree), MI355X gfx950.
// B=4, S=4096, H=8, D=64, f32.
//
// v10: attn32 scoring rebuilt around a multi-value butterfly reduction.
//  - 13 level-scores/query = 13 independent 16-lane reductions: folded
//    butterfly computes all in 15 shfls (vs 52), score j lands on lane j.
//  - ONE __expf per lane per query (vs 13 per lane): lane j exponentiates
//    its own score after a masked shfl-max; denom via red16; 13 broadcasts
//    feed the weighting.
//  - weighting vc loads shared between the two queries (13 vs 26).
//  - level-1..4 score dots interleaved into the tree-ladder barriers so
//    idle waves do scoring work.
//  - chunk5 / build_hi_half unchanged from v9 (not the bottleneck).
//  - R6 note: ~43us/iter fillBufferAligned (256MiB ws poison) is harness
//    reset inside the timed loop — fixed floor.
// hi layout per bh (NHI=254 rows): [0,128)=l5, [128,192)=l6, [192,224)=l7,
// [224,240)=l8, [240,248)=l9, [248,252)=l10, [252,254)=l11.

#define S 4096
#define H 8
#define D 64
#define B 4
#define NBH 32
#define NHI 254
#define SCALE 0.125f
#define ROWF 68          // padded LDS row stride in floats

__device__ inline float red16(float x) {
    x += __shfl_xor(x, 1);
    x += __shfl_xor(x, 2);
    x += __shfl_xor(x, 4);
    x += __shfl_xor(x, 8);
    return x;
}

__device__ inline float dot4(const float4 a, const float4 b) {
    return a.x * b.x + a.y * b.y + a.z * b.z + a.w * b.w;
}

__device__ inline float4 shfl_xor4(const float4 x, int m) {
    float4 r;
    r.x = __shfl_xor(x.x, m);
    r.y = __shfl_xor(x.y, m);
    r.z = __shfl_xor(x.z, m);
    r.w = __shfl_xor(x.w, m);
    return r;
}

__device__ inline float4 sel4(bool c, const float4 a, const float4 b) {
    float4 r;
    r.x = c ? a.x : b.x;
    r.y = c ? a.y : b.y;
    r.z = c ? a.z : b.z;
    r.w = c ? a.w : b.w;
    return r;
}

// Multi-value butterfly: p[0..15] per lane; returns (on lane sub of each
// 16-lane group) the 16-lane sum of slot `sub`. 15 shfl + 15 add.
__device__ inline float bfly16(float* p, int sub) {
    int b = (sub >> 3) & 1;
#pragma unroll
    for (int j = 0; j < 8; ++j) {
        float mine = b ? p[j + 8] : p[j];
        float send = b ? p[j] : p[j + 8];
        p[j] = mine + __shfl_xor(send, 8);
    }
    b = (sub >> 2) & 1;
#pragma unroll
    for (int j = 0; j < 4; ++j) {
        float mine = b ? p[j + 4] : p[j];
        float send = b ? p[j] : p[j + 4];
        p[j] = mine + __shfl_xor(send, 4);
    }
    b = (sub >> 1) & 1;
#pragma unroll
    for (int j = 0; j < 2; ++j) {
        float mine = b ? p[j + 2] : p[j];
        float send = b ? p[j] : p[j + 2];
        p[j] = mine + __shfl_xor(send, 2);
    }
    b = sub & 1;
    {
        float mine = b ? p[1] : p[0];
        float send = b ? p[0] : p[1];
        p[0] = mine + __shfl_xor(send, 1);
    }
    return p[0];
}

// parent(k,v) from two children: softmax-weighted merge (16-lane reduce).
__device__ inline void combine(const float4 k0, const float4 k1,
                               const float4 v0, const float4 v1,
                               float4& kp, float4& vp) {
    kp.x = 0.5f * (k0.x + k1.x);
    kp.y = 0.5f * (k0.y + k1.y);
    kp.z = 0.5f * (k0.z + k1.z);
    kp.w = 0.5f * (k0.w + k1.w);
    float pss = red16(dot4(kp, kp)) * SCALE;
    float p0  = red16(dot4(kp, k0)) * SCALE;
    float p1  = red16(dot4(kp, k1)) * SCALE;
    float m  = fmaxf(pss, fmaxf(p0, p1));
    float es = __expf(pss - m), e0 = __expf(p0 - m), e1 = __expf(p1 - m);
    float inv = 1.0f / (es + e0 + e1 + 1e-9f);
    float h = 0.5f * es;
    vp.x = ((h + e0) * v0.x + (h + e1) * v1.x) * inv;
    vp.y = ((h + e0) * v0.y + (h + e1) * v1.y) * inv;
    vp.z = ((h + e0) * v0.z + (h + e1) * v1.z) * inv;
    vp.w = ((h + e0) * v0.w + (h + e1) * v1.w) * inv;
}

// K1: per (bh, pair of 32-leaf chunks): levels 1..5, write l5 roots.
__global__ __launch_bounds__(256, 6) void chunk5(
    const float* __restrict__ k, const float* __restrict__ v,
    float* __restrict__ khi, float* __restrict__ vhi)
{
    __shared__ float l4k[4 * ROWF], l4v[4 * ROWF];   // 2 chunks x 2 l4 rows
    const int t = threadIdx.x;
    const int sub = t & 15;
    const int pg = t >> 4;
    const int blk = blockIdx.x;
    const int pair = blk & 63;
    const int bh = blk >> 6;
    const int b = bh >> 3, h = bh & 7;
    const int csel = pg >> 3;           // 0 or 1
    const int jg = pg & 7;
    const int c = pair * 2 + csel;      // 0..127

    const int s0 = c * 32 + 4 * jg;
    const size_t a0 = ((((size_t)b * S + s0) * H + h) * D) + sub * 4;
    float4 kA = *(const float4*)(k + a0);
    float4 kB = *(const float4*)(k + a0 + H * D);
    float4 kC = *(const float4*)(k + a0 + 2 * H * D);
    float4 kD = *(const float4*)(k + a0 + 3 * H * D);
    float4 vA = *(const float4*)(v + a0);
    float4 vB = *(const float4*)(v + a0 + H * D);
    float4 vC = *(const float4*)(v + a0 + 2 * H * D);
    float4 vD = *(const float4*)(v + a0 + 3 * H * D);

    float4 k1a, v1a, k1b, v1b, k2, v2;
    combine(kA, kB, vA, vB, k1a, v1a);         // l1 node 2jg
    combine(kC, kD, vC, vD, k1b, v1b);         // l1 node 2jg+1
    combine(k1a, k1b, v1a, v1b, k2, v2);       // l2 node jg

    // l3 node jg>>1 via xor16 (partner group jg^1, same wave)
    float4 p2k = shfl_xor4(k2, 16), p2v = shfl_xor4(v2, 16);
    float4 k3, v3;
    combine(sel4(jg & 1, p2k, k2), sel4(jg & 1, k2, p2k),
            sel4(jg & 1, p2v, v2), sel4(jg & 1, v2, p2v), k3, v3);

    // l4 node jg>>2 via xor32 (partner group jg^2, same wave)
    float4 p3k = shfl_xor4(k3, 32), p3v = shfl_xor4(v3, 32);
    float4 k4, v4;
    combine(sel4(jg & 2, p3k, k3), sel4(jg & 2, k3, p3k),
            sel4(jg & 2, p3v, v3), sel4(jg & 2, v3, p3v), k4, v4);

    if ((jg & 3) == 0) {                       // one writer per l4 node
        int row = csel * 2 + (jg >> 2);
        *(float4*)(l4k + row * ROWF + sub * 4) = k4;
        *(float4*)(l4v + row * ROWF + sub * 4) = v4;
    }
    __syncthreads();
    if (jg == 0) {                             // l5 root of this chunk
        int r0 = csel * 2, r1 = csel * 2 + 1;
        float4 ka4 = *(const float4*)(l4k + r0 * ROWF + sub * 4);
        float4 kb4 = *(const float4*)(l4k + r1 * ROWF + sub * 4);
        float4 va4 = *(const float4*)(l4v + r0 * ROWF + sub * 4);
        float4 vb4 = *(const float4*)(l4v + r1 * ROWF + sub * 4);
        float4 kp, vp;
        combine(ka4, kb4, va4, vb4, kp, vp);
        size_t g = ((size_t)bh * NHI + c) * 64 + sub * 4;
        *(float4*)(khi + g) = kp;
        *(float4*)(vhi + g) = vp;
    }
}

// K2: 64 blocks. Block (bh, half) builds levels 6..11 for its disjoint
// 64-root half-subtree.
__global__ __launch_bounds__(256) void build_hi_half(
    float* __restrict__ khi, float* __restrict__ vhi)
{
    __shared__ float lk[64 * ROWF], lv[64 * ROWF];
    const int t = threadIdx.x;
    const int sub = t & 15;
    const int pg = t >> 4;
    const int bh = blockIdx.x >> 1;
    const int half = blockIdx.x & 1;
    size_t base = (size_t)bh * NHI * 64;
    const int rootO = half * 64;

    for (int i = t; i < 1024; i += 256) {
        int row = i >> 4, s16 = i & 15;
        *(float4*)(lk + row * ROWF + s16 * 4) =
            *(const float4*)(khi + base + (size_t)(rootO + row) * 64 + s16 * 4);
        *(float4*)(lv + row * ROWF + s16 * 4) =
            *(const float4*)(vhi + base + (size_t)(rootO + row) * 64 + s16 * 4);
    }
    __syncthreads();

#pragma unroll
    for (int tt = 1; tt <= 6; ++tt) {
        int nodes = 64 >> tt;                 // 32,16,8,4,2,1 (per half)
        int off = 256 - (256 >> tt);          // 128,192,224,240,248,252
        for (int j = pg; j < nodes; j += 16) {
            int r0 = (2 * j) << (tt - 1);
            int r1 = (2 * j + 1) << (tt - 1);
            float4 k0 = *(const float4*)(lk + r0 * ROWF + sub * 4);
            float4 k1 = *(const float4*)(lk + r1 * ROWF + sub * 4);
            float4 v0 = *(const float4*)(lv + r0 * ROWF + sub * 4);
            float4 v1 = *(const float4*)(lv + r1 * ROWF + sub * 4);
            float4 kp, vp;
            combine(k0, k1, v0, v1, kp, vp);
            *(float4*)(lk + (j << tt) * ROWF + sub * 4) = kp;
            *(float4*)(lv + (j << tt) * ROWF + sub * 4) = vp;
            size_t g = base + (size_t)(off + half * nodes + j) * 64 + sub * 4;
            *(float4*)(khi + g) = kp;
            *(float4*)(vhi + g) = vp;
        }
        __syncthreads();
    }
}

// K3: attention. Block = (bh, 32-query chunk). Group pg -> queries 2pg,2pg+1.
// Scoring via multi-value butterfly; ladder interleaved with score dots.
__global__ __launch_bounds__(256, 6) void attn32(
    const float* __restrict__ q, const float* __restrict__ k,
    const float* __restrict__ v,
    const float* __restrict__ khi, const float* __restrict__ vhi,
    float* __restrict__ out)
{
    __shared__ float tk[30 * ROWF], tv[30 * ROWF];   // l1:0-15 l2:16-23 l3:24-27 l4:28-29
    __shared__ float pk[7 * ROWF], pv[7 * ROWF];     // path l5..11
    const int t = threadIdx.x;
    const int sub = t & 15;
    const int pg = t >> 4;
    const int blk = blockIdx.x;
    const int c32 = blk & 127;
    const int bh = blk >> 7;
    const int b = bh >> 3, h = bh & 7;

    // stage path nodes (block-uniform): groups 0..6 -> pk, 8..14 -> pv
    {
        int pl = (pg < 7) ? pg : pg - 8;
        if (pl >= 0 && pl < 7 && pg != 7 && pg != 15) {
            if ((c32 >> pl) & 1) {
                int off = 256 - (256 >> pl);     // 0,128,192,224,240,248,252
                int node = off + ((c32 >> pl) ^ 1);
                size_t a = ((size_t)bh * NHI + node) * 64 + sub * 4;
                if (pg < 7) *(float4*)(pk + pl * ROWF + sub * 4) = *(const float4*)(khi + a);
                else        *(float4*)(pv + pl * ROWF + sub * 4) = *(const float4*)(vhi + a);
            }
        }
    }

    // leaves + queries (all global loads upfront)
    const int s0 = c32 * 32 + 2 * pg;
    const size_t a0 = ((((size_t)b * S + s0) * H + h) * D) + sub * 4;
    const float4 k0 = *(const float4*)(k + a0);
    const float4 k1 = *(const float4*)(k + a0 + H * D);
    const float4 v0 = *(const float4*)(v + a0);
    const float4 v1 = *(const float4*)(v + a0 + H * D);
    const float4 q0 = *(const float4*)(q + a0);
    const float4 q1 = *(const float4*)(q + a0 + H * D);

    // score partials: slot 0 = self, slot 1+l = level l (l=0..11)
    float p0[16], p1[16];
#pragma unroll
    for (int j = 0; j < 16; ++j) { p0[j] = 0.0f; p1[j] = 0.0f; }
    p0[0] = dot4(q0, k0);            // self, even query
    p1[0] = dot4(q1, k1);            // self, odd query
    p1[1] = dot4(q1, k0);            // l0 sibling (odd only; p0[1] stays 0)

    // l1 node pg from held leaf registers
    {
        float4 kp, vp;
        combine(k0, k1, v0, v1, kp, vp);
        *(float4*)(tk + pg * ROWF + sub * 4) = kp;
        *(float4*)(tv + pg * ROWF + sub * 4) = vp;
    }
    __syncthreads();

    // stage A: l1 score dots (all groups) + l2 combines (groups 0..7)
    if (pg & 1) {                            // level-1 bit of s
        float4 kc = *(const float4*)(tk + (pg ^ 1) * ROWF + sub * 4);
        p0[2] = dot4(q0, kc);
        p1[2] = dot4(q1, kc);
    }
    if (pg < 8) {
        float4 ka = *(const float4*)(tk + (2 * pg) * ROWF + sub * 4);
        float4 kb = *(const float4*)(tk + (2 * pg + 1) * ROWF + sub * 4);
        float4 va = *(const float4*)(tv + (2 * pg) * ROWF + sub * 4);
        float4 vb = *(const float4*)(tv + (2 * pg + 1) * ROWF + sub * 4);
        float4 kp, vp;
        combine(ka, kb, va, vb, kp, vp);
        *(float4*)(tk + (16 + pg) * ROWF + sub * 4) = kp;
        *(float4*)(tv + (16 + pg) * ROWF + sub * 4) = vp;
    }
    __syncthreads();

    // stage B: l2 score dots + l3 combines (groups 0..3)
    if ((pg >> 1) & 1) {
        float4 kc = *(const float4*)(tk + (16 + ((pg >> 1) ^ 1)) * ROWF + sub * 4);
        p0[3] = dot4(q0, kc);
        p1[3] = dot4(q1, kc);
    }
    if (pg < 4) {
        float4 ka = *(const float4*)(tk + (16 + 2 * pg) * ROWF + sub * 4);
        float4 kb = *(const float4*)(tk + (16 + 2 * pg + 1) * ROWF + sub * 4);
        float4 va = *(const float4*)(tv + (16 + 2 * pg) * ROWF + sub * 4);
        float4 vb = *(const float4*)(tv + (16 + 2 * pg + 1) * ROWF + sub * 4);
        float4 kp, vp;
        combine(ka, kb, va, vb, kp, vp);
        *(float4*)(tk + (24 + pg) * ROWF + sub * 4) = kp;
        *(float4*)(tv + (24 + pg) * ROWF + sub * 4) = vp;
    }
    __syncthreads();

    // stage C: l3 score dots + l4 combines (groups 0..1)
    if ((pg >> 2) & 1) {
        float4 kc = *(const float4*)(tk + (24 + ((pg >> 2) ^ 1)) * ROWF + sub * 4);
        p0[4] = dot4(q0, kc);
        p1[4] = dot4(q1, kc);
    }
    if (pg < 2) {
        float4 ka = *(const float4*)(tk + (24 + 2 * pg) * ROWF + sub * 4);
        float4 kb = *(const float4*)(tk + (24 + 2 * pg + 1) * ROWF + sub * 4);
        float4 va = *(const float4*)(tv + (24 + 2 * pg) * ROWF + sub * 4);
        float4 vb = *(const float4*)(tv + (24 + 2 * pg + 1) * ROWF + sub * 4);
        float4 kp, vp;
        combine(ka, kb, va, vb, kp, vp);
        *(float4*)(tk + (28 + pg) * ROWF + sub * 4) = kp;
        *(float4*)(tv + (28 + pg) * ROWF + sub * 4) = vp;
    }
    __syncthreads();

    // stage D: l4 score dots + path dots (l5..11)
    if ((pg >> 3) & 1) {
        float4 kc = *(const float4*)(tk + (28 + ((pg >> 3) ^ 1)) * ROWF + sub * 4);
        p0[5] = dot4(q0, kc);
        p1[5] = dot4(q1, kc);
    }
#pragma unroll
    for (int l = 5; l <= 11; ++l) {
        if ((c32 >> (l - 5)) & 1) {          // == bit l of s, block-uniform
            float4 kc = *(const float4*)(pk + (l - 5) * ROWF + sub * 4);
            p0[l + 1] = dot4(q0, kc);
            p1[l + 1] = dot4(q1, kc);
        }
    }

    // butterfly: lane sub holds the 16-lane sum of its slot
    float sc0 = bfly16(p0, sub) * SCALE;
    float sc1 = bfly16(p1, sub) * SCALE;

    // per-lane slot validity (slot 0 self; slot 1+l level l)
    const bool vcom =
        (sub == 0) ||
        (sub >= 2 && sub <= 5 && ((pg >> (sub - 2)) & 1)) ||
        (sub >= 6 && sub <= 12 && ((c32 >> (sub - 6)) & 1));
    const bool ok0 = vcom;
    const bool ok1 = vcom || (sub == 1);

    float xm0 = ok0 ? sc0 : -1e38f;
    float xm1 = ok1 ? sc1 : -1e38f;
    xm0 = fmaxf(xm0, __shfl_xor(xm0, 1)); xm1 = fmaxf(xm1, __shfl_xor(xm1, 1));
    xm0 = fmaxf(xm0, __shfl_xor(xm0, 2)); xm1 = fmaxf(xm1, __shfl_xor(xm1, 2));
    xm0 = fmaxf(xm0, __shfl_xor(xm0, 4)); xm1 = fmaxf(xm1, __shfl_xor(xm1, 4));
    xm0 = fmaxf(xm0, __shfl_xor(xm0, 8)); xm1 = fmaxf(xm1, __shfl_xor(xm1, 8));

    // one exp per lane per query
    float e0 = ok0 ? __expf(sc0 - xm0) : 0.0f;
    float e1 = ok1 ? __expf(sc1 - xm1) : 0.0f;
    float d0 = red16(e0);
    float d1 = red16(e1);

    // weighting: vc loads shared between the two queries
    float4 acc0, acc1;
    {
        float w0 = __shfl(e0, 0, 16);
        float w1 = __shfl(e1, 0, 16);
        acc0.x = w0 * v0.x; acc0.y = w0 * v0.y;
        acc0.z = w0 * v0.z; acc0.w = w0 * v0.w;
        acc1.x = w1 * v1.x; acc1.y = w1 * v1.y;
        acc1.z = w1 * v1.z; acc1.w = w1 * v1.w;
        float wl = __shfl(e1, 1, 16);        // l0 sibling (odd query)
        acc1.x += wl * v0.x; acc1.y += wl * v0.y;
        acc1.z += wl * v0.z; acc1.w += wl * v0.w;
    }
#pragma unroll
    for (int l = 1; l <= 4; ++l) {
        if ((pg >> (l - 1)) & 1) {
            int loc = (l == 1) ? (pg ^ 1)
                    : (l == 2) ? (16 + ((pg >> 1) ^ 1))
                    : (l == 3) ? (24 + ((pg >> 2) ^ 1))
                               : (28 + ((pg >> 3) ^ 1));
            float4 vc = *(const float4*)(tv + loc * ROWF + sub * 4);
            float w0 = __shfl(e0, l + 1, 16);
            float w1 = __shfl(e1, l + 1, 16);
            acc0.x += w0 * vc.x; acc0.y += w0 * vc.y;
            acc0.z += w0 * vc.z; acc0.w += w0 * vc.w;
            acc1.x += w1 * vc.x; acc1.y += w1 * vc.y;
            acc1.z += w1 * vc.z; acc1.w += w1 * vc.w;
        }
    }
#pragma unroll
    for (int l = 5; l <= 11; ++l) {
        if ((c32 >> (l - 5)) & 1) {
            float4 vc = *(const float4*)(pv + (l - 5) * ROWF + sub * 4);
            float w0 = __shfl(e0, l + 1, 16);
            float w1 = __shfl(e1, l + 1, 16);
            acc0.x += w0 * vc.x; acc0.y += w0 * vc.y;
            acc0.z += w0 * vc.z; acc0.w += w0 * vc.w;
            acc1.x += w1 * vc.x; acc1.y += w1 * vc.y;
            acc1.z += w1 * vc.z; acc1.w += w1 * vc.w;
        }
    }

    float i0 = 1.0f / d0, i1 = 1.0f / d1;
    float4 o0, o1;
    o0.x = acc0.x * i0; o0.y = acc0.y * i0;
    o0.z = acc0.z * i0; o0.w = acc0.w * i0;
    o1.x = acc1.x * i1; o1.y = acc1.y * i1;
    o1.z = acc1.z * i1; o1.w = acc1.w * i1;
    *(float4*)(out + a0) = o0;
    *(float4*)(out + a0 + H * D) = o1;
}

extern "C" void kernel_launch(void* const* d_in, const int* in_sizes, int n_in,
                              void* d_out, int out_size, void* d_ws, size_t ws_size,
                              hipStream_t stream) {
    const float* q = (const float*)d_in[0];
    const float* k = (const float*)d_in[1];
    const float* v = (const float*)d_in[2];
    float* outp = (float*)d_out;
    float* khi = (float*)d_ws;                      // 32*254*64 f32 ~= 2.1 MB
    float* vhi = khi + (size_t)NBH * NHI * D;

    hipLaunchKernelGGL(chunk5, dim3(NBH * 64), dim3(256), 0, stream,
                       k, v, khi, vhi);
    hipLaunchKernelGGL(build_hi_half, dim3(NBH * 2), dim3(256), 0, stream,
                       khi, vhi);
    hipLaunchKernelGGL(attn32, dim3(NBH * 128), dim3(256), 0, stream,
                       q, k, v, khi, vhi, outp);
}